// Round 1
// baseline (318.246 us; speedup 1.0000x reference)
//
#include <hip/hip_runtime.h>

// BilateralFilter: 8 x 1024 x 1024 x 3 fp32, D=9 (radius 4), sigma_color =
// sigma_space = 75, reflect padding, taps limited to dy*dy+dx*dx <= 16 (49 taps).

namespace {
constexpr int Himg = 1024;
constexpr int Wimg = 1024;
constexpr int CHN  = 3;
constexpr int RAD  = 4;

// 64x4 output tile per 256-thread block; wave = one 64-px row (coalesced).
constexpr int BXT = 64;
constexpr int BYT = 4;
constexpr int TW  = BXT + 2 * RAD;   // 72 pixels wide (with halo)
constexpr int TH  = BYT + 2 * RAD;   // 12 rows (with halo)
constexpr int TWF = TW * CHN;        // 216 floats per tile row
constexpr int LDSF = TH * TWF;       // 2592 floats = 10368 B LDS

constexpr float LOG2E = 1.4426950408889634f;
constexpr float COEFF = -0.5f / (75.0f * 75.0f);   // sigma_color == sigma_space
constexpr float KC = COEFF * LOG2E;                // color term, folded log2(e)
constexpr float KS = COEFF * LOG2E;                // space term, folded log2(e)
}

__device__ __forceinline__ int reflect_idx(int i, int n) {
    // radius << n, so a single fold suffices (jnp.pad mode='reflect')
    i = (i < 0) ? -i : i;
    i = (i >= n) ? (2 * n - 2 - i) : i;
    return i;
}

__global__ __launch_bounds__(256, 4)
void bilateral_kernel(const float* __restrict__ in, float* __restrict__ out) {
    __shared__ float tile[TH][TWF];

    const int tid = threadIdx.x;
    const int x0  = blockIdx.x * BXT;
    const int y0  = blockIdx.y * BYT;
    const int b   = blockIdx.z;

    const float* __restrict__ img = in + (size_t)b * Himg * Wimg * CHN;

    // ---- stage tile (with reflect halo) into LDS, coalesced dword loads ----
    for (int i = tid; i < LDSF; i += 256) {
        const int row = i / TWF;
        const int cf  = i - row * TWF;
        const int px  = cf / CHN;
        const int ch  = cf - px * CHN;
        const int gy  = reflect_idx(y0 - RAD + row, Himg);
        const int gx  = reflect_idx(x0 - RAD + px,  Wimg);
        tile[row][cf] = img[((size_t)gy * Wimg + gx) * CHN + ch];
    }
    __syncthreads();

    // ---- per-thread: one output pixel ----
    const int tx = tid & 63;   // wave = one full row of 64 px
    const int ty = tid >> 6;

    const float* __restrict__ cp = &tile[ty + RAD][(tx + RAD) * CHN];
    const float c0 = cp[0], c1 = cp[1], c2 = cp[2];

    float n0 = 0.0f, n1 = 0.0f, n2 = 0.0f, den = 0.0f;

#pragma unroll
    for (int dy = -RAD; dy <= RAD; ++dy) {
        const float* __restrict__ rp = &tile[ty + RAD + dy][(tx + RAD) * CHN];
#pragma unroll
        for (int dx = -RAD; dx <= RAD; ++dx) {
            constexpr int RR = RAD * RAD;
            const int r2 = dy * dy + dx * dx;
            if (r2 > RR) continue;           // compile-time pruned (49 taps live)

            const float b0 = rp[dx * CHN + 0];
            const float b1 = rp[dx * CHN + 1];
            const float b2 = rp[dx * CHN + 2];

            // L1 color distance; fabs folds into VALU input modifiers
            const float diff = fabsf(b0 - c0) + fabsf(b1 - c1) + fabsf(b2 - c2);

            // w = exp(coeff*diff^2 + coeff*r2), via native v_exp_f32:
            //   exp2( KC*diff^2 + (KS*r2) )   with KS*r2 a compile-time literal
            const float w = __builtin_amdgcn_exp2f(fmaf(diff * diff, KC, KS * (float)r2));

            n0 = fmaf(w, b0, n0);
            n1 = fmaf(w, b1, n1);
            n2 = fmaf(w, b2, n2);
            den += w;
        }
    }

    const float inv = 1.0f / den;   // den >= 1 (center tap weight = 1)
    const size_t o = ((size_t)(b * Himg + y0 + ty) * Wimg + (x0 + tx)) * CHN;
    out[o + 0] = n0 * inv;
    out[o + 1] = n1 * inv;
    out[o + 2] = n2 * inv;
}

extern "C" void kernel_launch(void* const* d_in, const int* in_sizes, int n_in,
                              void* d_out, int out_size, void* d_ws, size_t ws_size,
                              hipStream_t stream) {
    const float* in = (const float*)d_in[0];
    float* out = (float*)d_out;

    const int B = in_sizes[0] / (Himg * Wimg * CHN);   // = 8

    dim3 grid(Wimg / BXT, Himg / BYT, B);   // 16 x 256 x 8
    dim3 block(256);
    bilateral_kernel<<<grid, block, 0, stream>>>(in, out);
}